// Round 1
// 277.505 us; speedup vs baseline: 1.0154x; 1.0154x over previous
//
#include <hip/hip_runtime.h>

// ---------------------------------------------------------------------------
// GATv2 (2 layers) + mean-pool + MLP for MI355X.
// N=50000 nodes, E=800000 edges (+N self loops), IN=128, HID=64, HEADS=2,
// OUT=3, 64 graphs. Output: [64,3] float32.
// R1: k_agg2 pool atomic storm fixed (LDS pre-reduction). 1128 -> 803 us.
// R2: CSR + per-node online softmax; edge phases fused.   803 -> 515 us.
// R3: fused1 2-edge ILP + reg src cache + W2-proj fused.   515 -> 394 us.
// R4: fused1 2 nodes/wave + 4-edge ILP + batched softmax.  394 -> 368 us.
// R5: gemm 128x128 reg-blocked (LDS 72KB->16KB).            368 -> 343 us.
// R6: DPP rotate-reduce + exp2 domain; gemm 64x128/4x8.     343 -> 337 us.
// R7: 8-edge unroll flat. R8-R10: degree-sort detour regressed; reverted.
// R11: 3-phase parallel scan (single-block scan was 100us!). 422 -> 329 us.
// R12: xl1 message table bf16 (gather 512->256B/edge).       329 -> 326 us.
// R13: k_fill atomic-free (rank from k_deg atomic return); gemm merged
//      (x@W1l AND x@W1r per x-tile).                         326 -> 282 us.
// R14: GEMM moved to matrix cores. k_gemm128 was MfmaUtil=0, 43% VALUBusy,
//      53 TF = 34% of fp32 vector peak (62 us). Now: k_cvt splits x and W
//      into bf16 hi+lo (x=xh+xl, W=Wh+Wl, residual-of-residual ~2^-18),
//      k_gmfma computes xh@Wh + xh@Wl + xl@Wh via mfma_f32_16x16x32_bf16 —
//      fp32-class accuracy at matrix-core speed. LDS-free: B-frags read from
//      L2-resident 128KB transposed Wt[col][k]; A-frags straight from xh/xl.
// ---------------------------------------------------------------------------

#define NGRAPH 64
#define LOG2E 1.4426950408889634f

// v_mov_dpp row_ror:k (16-lane rows). Valid reduce permutation for
// commutative ops; leaves every lane of the row with the full result.
#define DPP_ROR(C, x) \
  __int_as_float(__builtin_amdgcn_update_dpp(0, __float_as_int(x), (0x120 | C), 0xF, 0xF, false))

__device__ __forceinline__ float rowsum16(float v) {
  v += DPP_ROR(8, v);
  v += DPP_ROR(4, v);
  v += DPP_ROR(2, v);
  v += DPP_ROR(1, v);
  return v;
}

__device__ __forceinline__ unsigned bf16rne(float f) {
  unsigned u = __float_as_uint(f);
  return (u + 0x7FFFu + ((u >> 16) & 1u)) >> 16;
}

typedef __attribute__((ext_vector_type(8))) short bf16x8;
typedef __attribute__((ext_vector_type(4))) float f32x4;

// ---------------------------------------------------------------------------
// R13: the atomic's return value IS this edge's rank among its dst's edges.
__global__ void k_deg(const int* __restrict__ ei, int E, int Et,
                      int* __restrict__ deg, int* __restrict__ rank) {
  int e = blockIdx.x * blockDim.x + threadIdx.x;
  if (e >= Et) return;
  int d = (e < E) ? ei[E + e] : (e - E);  // dst only
  rank[e] = atomicAdd(&deg[d], 1);        // coalesced store of the rank
}

// ---------------------------------------------------------------------------
// 3-phase parallel exclusive scan of deg[0..n) -> row_ptr[0..n].
__global__ __launch_bounds__(256) void k_scan_part(const int* __restrict__ deg,
                                                   int* __restrict__ bsum, int n) {
  __shared__ int sd[256];
  int t = threadIdx.x;
  int i = blockIdx.x * 1024 + t * 4;
  int s = 0;
  if (i + 4 <= n) {
    int4 d = *(const int4*)&deg[i];
    s = d.x + d.y + d.z + d.w;
  } else {
    for (int j = i; j < min(i + 4, n); ++j) s += deg[j];
  }
  sd[t] = s;
  __syncthreads();
  for (int off = 128; off; off >>= 1) {
    if (t < off) sd[t] += sd[t + off];
    __syncthreads();
  }
  if (t == 0) bsum[blockIdx.x] = sd[0];
}

__global__ __launch_bounds__(64) void k_scan_top(int* __restrict__ bsum, int nb) {
  __shared__ int s[64];
  int t = threadIdx.x;
  s[t] = (t < nb) ? bsum[t] : 0;
  __syncthreads();
  int acc = 0;
  for (int j = 0; j < t; ++j) acc += s[j];
  if (t < nb) bsum[t] = acc;
}

__global__ __launch_bounds__(256) void k_scan_write(const int* __restrict__ deg,
                                                    const int* __restrict__ bsum,
                                                    int* __restrict__ row_ptr, int n) {
  __shared__ int sd[256];
  int t = threadIdx.x;
  int i = blockIdx.x * 1024 + t * 4;
  int4 d = make_int4(0, 0, 0, 0);
  bool full = (i + 4 <= n);
  if (full) d = *(const int4*)&deg[i];
  else {
    if (i + 0 < n) d.x = deg[i + 0];
    if (i + 1 < n) d.y = deg[i + 1];
    if (i + 2 < n) d.z = deg[i + 2];
    if (i + 3 < n) d.w = deg[i + 3];
  }
  int s = d.x + d.y + d.z + d.w;
  sd[t] = s;
  __syncthreads();
  for (int off = 1; off < 256; off <<= 1) {  // Hillis-Steele inclusive
    int v = (t >= off) ? sd[t - off] : 0;
    __syncthreads();
    sd[t] += v;
    __syncthreads();
  }
  int ex = sd[t] - s + bsum[blockIdx.x];
  int4 r;
  r.x = ex;
  r.y = ex + d.x;
  r.z = r.y + d.y;
  r.w = r.z + d.z;
  if (full) {
    *(int4*)&row_ptr[i] = r;
    if (i + 4 == n) row_ptr[n] = r.w + d.w;
  } else if (i < n) {
    int run = ex;
    int vals[4] = {d.x, d.y, d.z, d.w};
    for (int j = 0; j < 4 && i + j < n; ++j) {
      row_ptr[i + j] = run;
      run += vals[j];
    }
    if (i <= n && i + 4 > n) row_ptr[n] = run;
  }
}

// R13: no atomic — slot is row_ptr[d] + precomputed rank.
__global__ void k_fill(const int* __restrict__ ei, int E, int Et,
                       const int* __restrict__ row_ptr,
                       const int* __restrict__ rank,
                       int* __restrict__ csr_src) {
  int e = blockIdx.x * blockDim.x + threadIdx.x;
  if (e >= Et) return;
  int s, d;
  if (e < E) { s = ei[e]; d = ei[E + e]; }
  else       { s = e - E; d = s; }
  csr_src[row_ptr[d] + rank[e]] = s;
}

// ---------------------------------------------------------------------------
// R14 prep: split-bf16 decomposition.
//   blocks [0, xblk):      x[i] -> xh (bf16 of x) and xlo (bf16 of residual)
//   blocks [xblk, +128):   W1l|W1r -> Wt_hi/Wt_lo, TRANSPOSED [col][k] so the
//                          GEMM's B-fragment (8 contiguous k per lane) is one
//                          16B load. cols 0..127 = W1l, 128..255 = W1r.
__global__ __launch_bounds__(256) void k_cvt(const float* __restrict__ x,
                                             const float* __restrict__ W1l,
                                             const float* __restrict__ W1r,
                                             unsigned short* __restrict__ xh,
                                             unsigned short* __restrict__ xlo,
                                             unsigned short* __restrict__ wh,
                                             unsigned short* __restrict__ wlo,
                                             int total_x, int xblk) {
  if ((int)blockIdx.x < xblk) {
    int i = (blockIdx.x * 256 + threadIdx.x) * 8;
    if (i + 8 <= total_x) {
      float4 a = *(const float4*)&x[i];
      float4 b = *(const float4*)&x[i + 4];
      float f[8] = {a.x, a.y, a.z, a.w, b.x, b.y, b.z, b.w};
      unsigned hv[8], lv[8];
#pragma unroll
      for (int j = 0; j < 8; ++j) {
        hv[j] = bf16rne(f[j]);
        float r = f[j] - __uint_as_float(hv[j] << 16);
        lv[j] = bf16rne(r);
      }
      uint4 ph, pl;
      ph.x = hv[0] | (hv[1] << 16); ph.y = hv[2] | (hv[3] << 16);
      ph.z = hv[4] | (hv[5] << 16); ph.w = hv[6] | (hv[7] << 16);
      pl.x = lv[0] | (lv[1] << 16); pl.y = lv[2] | (lv[3] << 16);
      pl.z = lv[4] | (lv[5] << 16); pl.w = lv[6] | (lv[7] << 16);
      *(uint4*)&xh[i] = ph;
      *(uint4*)&xlo[i] = pl;
    } else {
      for (int j = i; j < total_x; ++j) {
        float f = x[j];
        unsigned h = bf16rne(f);
        xh[j] = (unsigned short)h;
        xlo[j] = (unsigned short)bf16rne(f - __uint_as_float(h << 16));
      }
    }
  } else {
    int j = ((int)blockIdx.x - xblk) * 256 + threadIdx.x;  // [0, 256*128)
    if (j < 256 * 128) {
      int col = j >> 7, k = j & 127;
      float w = (col < 128) ? W1l[k * 128 + col] : W1r[k * 128 + (col - 128)];
      unsigned h = bf16rne(w);
      wh[j] = (unsigned short)h;
      wlo[j] = (unsigned short)bf16rne(w - __uint_as_float(h << 16));
    }
  }
}

// ---------------------------------------------------------------------------
// R14 GEMM on matrix cores. Per block: 64 rows x 256 cols. 4 waves, wave w
// owns cols [w*64, w*64+64). Waves 0-1 produce xl1 = x@W1l (stored bf16),
// waves 2-3 produce xr1 = x@W1r (fp32). LDS-free: A frags from xh/xlo
// (L2/L3-hot, written by k_cvt), B frags from the 128KB L2-resident Wt.
// 3 MFMA passes per frag pair: xh*Wh + xh*Wl + xl*Wh (fp32-class accuracy).
// mfma_f32_16x16x32_bf16 layouts (learn_hip m89/m91-verified):
//   A: row = lane&15, k = (lane>>4)*8 + j   (8 contiguous bf16 per lane)
//   B: col = lane&15, k = (lane>>4)*8 + j
//   D: col = lane&15, row = (lane>>4)*4 + reg
__global__ __launch_bounds__(256) void k_gmfma(const unsigned short* __restrict__ xh,
                                               const unsigned short* __restrict__ xlo,
                                               const unsigned short* __restrict__ wh,
                                               const unsigned short* __restrict__ wlo,
                                               unsigned short* __restrict__ outl,
                                               float* __restrict__ outr, int n) {
  int wid = threadIdx.x >> 6;
  int lane = threadIdx.x & 63;
  int lr = lane & 15;
  int lk = (lane >> 4) * 8;
  int r0 = blockIdx.x * 64;
  int wcol = wid * 64;

  int rows[4];
#pragma unroll
  for (int m = 0; m < 4; ++m) rows[m] = min(r0 + m * 16 + lr, n - 1);

  f32x4 acc[4][4] = {};

#pragma unroll
  for (int kc = 0; kc < 4; ++kc) {
    int ko = kc * 32 + lk;
    bf16x8 ah[4], al[4], bh[4], bl[4];
#pragma unroll
    for (int m = 0; m < 4; ++m) {
      ah[m] = *(const bf16x8*)&xh[(size_t)rows[m] * 128 + ko];
      al[m] = *(const bf16x8*)&xlo[(size_t)rows[m] * 128 + ko];
    }
#pragma unroll
    for (int f = 0; f < 4; ++f) {
      int c = wcol + f * 16 + lr;
      bh[f] = *(const bf16x8*)&wh[c * 128 + ko];
      bl[f] = *(const bf16x8*)&wlo[c * 128 + ko];
    }
#pragma unroll
    for (int m = 0; m < 4; ++m)
#pragma unroll
      for (int f = 0; f < 4; ++f) {
        acc[m][f] = __builtin_amdgcn_mfma_f32_16x16x32_bf16(ah[m], bh[f], acc[m][f], 0, 0, 0);
        acc[m][f] = __builtin_amdgcn_mfma_f32_16x16x32_bf16(ah[m], bl[f], acc[m][f], 0, 0, 0);
        acc[m][f] = __builtin_amdgcn_mfma_f32_16x16x32_bf16(al[m], bh[f], acc[m][f], 0, 0, 0);
      }
  }

  int rbase = (lane >> 4) * 4;
  if (wid < 2) {
#pragma unroll
    for (int m = 0; m < 4; ++m)
#pragma unroll
      for (int f = 0; f < 4; ++f) {
        int col = wcol + f * 16 + lr;
#pragma unroll
        for (int i = 0; i < 4; ++i) {
          int row = r0 + m * 16 + rbase + i;
          if (row < n)
            outl[(size_t)row * 128 + col] = (unsigned short)bf16rne(acc[m][f][i]);
        }
      }
  } else {
#pragma unroll
    for (int m = 0; m < 4; ++m)
#pragma unroll
      for (int f = 0; f < 4; ++f) {
        int col = (wid - 2) * 64 + f * 16 + lr;
#pragma unroll
        for (int i = 0; i < 4; ++i) {
          int row = r0 + m * 16 + rbase + i;
          if (row < n)
            outr[(size_t)row * 128 + col] = acc[m][f][i];
        }
      }
  }
}

// ---------------------------------------------------------------------------
// fused layer-1 edge phase + layer-2 input projection.
// TWO nodes per wave: lanes 0-31 = node 2w, 32-63 = node 2w+1. Lane holds 4
// channels; 16-lane head groups = DPP rows. 4 edges/iter: clamp-free main
// loop to mindeg, clamped+masked tail to maxdeg. xl gathered as BF16x4
// (uint2, 8B/lane = 256B/row) and unpacked with shift/mask; acc fp32.
__global__ __launch_bounds__(256) void k_fused1(const unsigned short* __restrict__ xl,
                                                const float* __restrict__ xr,
                                                const int* __restrict__ row_ptr,
                                                const int* __restrict__ csr_src,
                                                const float* __restrict__ att1,
                                                const float* __restrict__ b1,
                                                const float* __restrict__ W2l,
                                                const float* __restrict__ W2r,
                                                float* __restrict__ xl2,
                                                float* __restrict__ xr2, int n) {
  int wid  = (blockIdx.x * 256 + threadIdx.x) >> 6;
  int lane = threadIdx.x & 63;
  int sub  = lane & 31;
  int node = min(wid * 2 + (lane >> 5), n - 1);  // dup of last node is benign
  int ch = sub * 4;
  const char* xlb = (const char*)xl;
  unsigned chb = (unsigned)sub * 8u;  // byte offset within 256B bf16 row
  float4 xrv = *(const float4*)&xr[(size_t)node * 128 + ch];
  float4 atv = *(const float4*)&att1[ch];
  atv.x *= LOG2E; atv.y *= LOG2E; atv.z *= LOG2E; atv.w *= LOG2E;
  int s0 = row_ptr[node];
  int deg = row_ptr[node + 1] - s0;  // >=1 (self-loop)
  int odeg = __shfl_xor(deg, 32);
  int mindeg = min(deg, odeg);  // wave-uniform
  int maxdeg = max(deg, odeg);  // wave-uniform
  const int* sp = csr_src + s0;

  float m = -1e30f, l = 0.f;
  float4 acc = make_float4(0.f, 0.f, 0.f, 0.f);

  float t0, t1, t2, t3;
#define UNPACK(dst, q)                                                  \
    dst.x = __uint_as_float(q.x << 16);                                 \
    dst.y = __uint_as_float(q.x & 0xFFFF0000u);                         \
    dst.z = __uint_as_float(q.y << 16);                                 \
    dst.w = __uint_as_float(q.y & 0xFFFF0000u);
#define LOGIT(p, v)                                                     \
    t0 = v.x + xrv.x; t0 = fmaxf(t0, 0.2f * t0);                        \
    t1 = v.y + xrv.y; t1 = fmaxf(t1, 0.2f * t1);                        \
    t2 = v.z + xrv.z; t2 = fmaxf(t2, 0.2f * t2);                        \
    t3 = v.w + xrv.w; t3 = fmaxf(t3, 0.2f * t3);                        \
    p = fmaf(t3, atv.w, fmaf(t2, atv.z, fmaf(t1, atv.y, t0 * atv.x)));

#define BODY(CLAMPED)                                                   \
  {                                                                     \
    int sA, sB, sC, sD;                                                 \
    if (CLAMPED) {                                                      \
      int dm1 = deg - 1;                                                \
      sA = sp[min(e + 0, dm1)];                                         \
      sB = sp[min(e + 1, dm1)];                                         \
      sC = sp[min(e + 2, dm1)];                                         \
      sD = sp[min(e + 3, dm1)];                                         \
    } else {                                                            \
      sA = sp[e + 0]; sB = sp[e + 1]; sC = sp[e + 2]; sD = sp[e + 3];   \
    }                                                                   \
    uint2 qa = *(const uint2*)(xlb + (((unsigned)sA << 8) + chb));      \
    uint2 qb = *(const uint2*)(xlb + (((unsigned)sB << 8) + chb));      \
    uint2 qc = *(const uint2*)(xlb + (((unsigned)sC << 8) + chb));      \
    uint2 qd = *(const uint2*)(xlb + (((unsigned)sD << 8) + chb));      \
    float4 xa, xb, xc, xd;                                              \
    UNPACK(xa, qa) UNPACK(xb, qb) UNPACK(xc, qc) UNPACK(xd, qd)         \
    float pa, pb, pc, pd;                                               \
    LOGIT(pa, xa) LOGIT(pb, xb) LOGIT(pc, xc) LOGIT(pd, xd)             \
    pa = rowsum16(pa);                                                  \
    pb = rowsum16(pb);                                                  \
    pc = rowsum16(pc);                                                  \
    pd = rowsum16(pd);                                                  \
    if (CLAMPED) {                                                      \
      pa = (e + 0 < deg) ? pa : -1e30f;                                 \
      pb = (e + 1 < deg) ? pb : -1e30f;                                 \
      pc = (e + 2 < deg) ? pc : -1e30f;                                 \
      pd = (e + 3 < deg) ? pd : -1e30f;                                 \
    }                                                                   \
    float mn = fmaxf(m, fmaxf(fmaxf(pa, pb), fmaxf(pc, pd)));           \
    float sc = exp2f(m - mn);                                           \
    float wa = exp2f(pa - mn);                                          \
    float wb = exp2f(pb - mn);                                          \
    float wc = exp2f(pc - mn);                                          \
    float wd = exp2f(pd - mn);                                          \
    acc.x = fmaf(wd, xd.x, fmaf(wc, xc.x, fmaf(wb, xb.x, fmaf(wa, xa.x, acc.x * sc)))); \
    acc.y = fmaf(wd, xd.y, fmaf(wc, xc.y, fmaf(wb, xb.y, fmaf(wa, xa.y, acc.y * sc)))); \
    acc.z = fmaf(wd, xd.z, fmaf(wc, xc.z, fmaf(wb, xb.z, fmaf(wa, xa.z, acc.z * sc)))); \
    acc.w = fmaf(wd, xd.w, fmaf(wc, xc.w, fmaf(wb, xb.w, fmaf(wa, xa.w, acc.w * sc)))); \
    l = fmaf(l, sc, wa + wb + wc + wd);                                 \
    m = mn;                                                             \
  }

  int e = 0;
  for (; e + 4 <= mindeg; e += 4) BODY(false)
  for (; e < maxdeg; e += 4) BODY(true)
#undef BODY
#undef LOGIT
#undef UNPACK

  float inv = 1.f / (l + 1e-16f);
  float4 b1v = *(const float4*)&b1[ch];
  float4 h;
  h.x = acc.x * inv + b1v.x; h.x = h.x > 0.f ? h.x : expm1f(h.x);
  h.y = acc.y * inv + b1v.y; h.y = h.y > 0.f ? h.y : expm1f(h.y);
  h.z = acc.z * inv + b1v.z; h.z = h.z > 0.f ? h.z : expm1f(h.z);
  h.w = acc.w * inv + b1v.w; h.w = h.w > 0.f ? h.w : expm1f(h.w);

  float4 u0 = *(const float4*)&W2l[ch * 3 + 0];
  float4 u1 = *(const float4*)&W2l[ch * 3 + 4];
  float4 u2 = *(const float4*)&W2l[ch * 3 + 8];
  float al0 = fmaf(h.w, u2.y, fmaf(h.z, u1.z, fmaf(h.y, u0.w, h.x * u0.x)));
  float al1 = fmaf(h.w, u2.z, fmaf(h.z, u1.w, fmaf(h.y, u1.x, h.x * u0.y)));
  float al2 = fmaf(h.w, u2.w, fmaf(h.z, u2.x, fmaf(h.y, u1.y, h.x * u0.z)));
  float4 v0 = *(const float4*)&W2r[ch * 3 + 0];
  float4 v1 = *(const float4*)&W2r[ch * 3 + 4];
  float4 v2 = *(const float4*)&W2r[ch * 3 + 8];
  float ar0 = fmaf(h.w, v2.y, fmaf(h.z, v1.z, fmaf(h.y, v0.w, h.x * v0.x)));
  float ar1 = fmaf(h.w, v2.z, fmaf(h.z, v1.w, fmaf(h.y, v1.x, h.x * v0.y)));
  float ar2 = fmaf(h.w, v2.w, fmaf(h.z, v2.x, fmaf(h.y, v1.y, h.x * v0.z)));
#pragma unroll
  for (int off = 1; off < 32; off <<= 1) {
    al0 += __shfl_xor(al0, off); al1 += __shfl_xor(al1, off);
    al2 += __shfl_xor(al2, off); ar0 += __shfl_xor(ar0, off);
    ar1 += __shfl_xor(ar1, off); ar2 += __shfl_xor(ar2, off);
  }
  if (sub == 0 && wid * 2 + (lane >> 5) < n) {
    *(float4*)&xl2[node * 4] = make_float4(al0, al1, al2, 0.f);
    *(float4*)&xr2[node * 4] = make_float4(ar0, ar1, ar2, 0.f);
  }
}

// ---------------------------------------------------------------------------
// fused layer-2 edge phase + mean-pool. 16 lanes per node (= one DPP row);
// per-lane online softmax (exp2 domain) over a 16-stride slice, DPP rotate
// merge of (m,l,acc3) states. Pool pre-reduced in LDS.
__global__ __launch_bounds__(256) void k_fused2(const float* __restrict__ xl2,
                                                const float* __restrict__ xr2,
                                                const int* __restrict__ row_ptr,
                                                const int* __restrict__ csr_src,
                                                const float* __restrict__ att2,
                                                const float* __restrict__ b2,
                                                const int* __restrict__ batch,
                                                float* __restrict__ gsum,
                                                float* __restrict__ gcnt, int n) {
  __shared__ float ls[NGRAPH * 3];
  __shared__ float lc[NGRAPH];
  int t = threadIdx.x;
  for (int i = t; i < NGRAPH * 3; i += 256) ls[i] = 0.f;
  for (int i = t; i < NGRAPH; i += 256) lc[i] = 0.f;
  __syncthreads();

  int node = (blockIdx.x * 256 + t) >> 4;  // 16 nodes per block
  int lane = t & 15;
  if (node < n) {
    float4 xrv = *(const float4*)&xr2[node * 4];
    float c0 = att2[0] * LOG2E, c1 = att2[1] * LOG2E, c2 = att2[2] * LOG2E;
    int s0 = row_ptr[node], s1 = row_ptr[node + 1];
    float m = -1e30f, l = 0.f, a0 = 0.f, a1 = 0.f, a2 = 0.f;
    for (int slot = s0 + lane; slot < s1; slot += 16) {
      int s = csr_src[slot];
      float4 xlv = *(const float4*)&xl2[s * 4];
      float t0 = xlv.x + xrv.x; t0 = fmaxf(t0, 0.2f * t0);
      float t1 = xlv.y + xrv.y; t1 = fmaxf(t1, 0.2f * t1);
      float t2 = xlv.z + xrv.z; t2 = fmaxf(t2, 0.2f * t2);
      float p = fmaf(t2, c2, fmaf(t1, c1, t0 * c0));
      float mn = fmaxf(m, p);
      float sc = exp2f(m - mn);
      float w  = exp2f(p - mn);
      a0 = a0 * sc + w * xlv.x;
      a1 = a1 * sc + w * xlv.y;
      a2 = a2 * sc + w * xlv.z;
      l = l * sc + w;
      m = mn;
    }
#define MERGE(C)                                                        \
    {                                                                   \
      float m2 = DPP_ROR(C, m);                                         \
      float l2 = DPP_ROR(C, l);                                         \
      float b0 = DPP_ROR(C, a0);                                        \
      float b1v = DPP_ROR(C, a1);                                       \
      float b2v = DPP_ROR(C, a2);                                       \
      float mn = fmaxf(m, m2);                                          \
      float sA = exp2f(m - mn);                                         \
      float sB = exp2f(m2 - mn);                                        \
      a0 = a0 * sA + b0 * sB;                                           \
      a1 = a1 * sA + b1v * sB;                                          \
      a2 = a2 * sA + b2v * sB;                                          \
      l = l * sA + l2 * sB;                                             \
      m = mn;                                                           \
    }
    MERGE(8) MERGE(4) MERGE(2) MERGE(1)
#undef MERGE
    if (lane == 0) {
      float inv = 1.f / (l + 1e-16f);
      float o0 = a0 * inv + b2[0];
      float o1 = a1 * inv + b2[1];
      float o2 = a2 * inv + b2[2];
      int b = batch[node];
      atomicAdd(&ls[b * 3 + 0], o0);
      atomicAdd(&ls[b * 3 + 1], o1);
      atomicAdd(&ls[b * 3 + 2], o2);
      atomicAdd(&lc[b], 1.f);
    }
  }
  __syncthreads();
  for (int i = t; i < NGRAPH * 3; i += 256)
    if (ls[i] != 0.f) atomicAdd(&gsum[i], ls[i]);
  for (int i = t; i < NGRAPH; i += 256)
    if (lc[i] != 0.f) atomicAdd(&gcnt[i], lc[i]);
}

// 1 block, 64 threads: per-graph mean + 2-layer MLP
__global__ __launch_bounds__(64) void k_mlp(const float* __restrict__ gsum,
                                            const float* __restrict__ gcnt,
                                            const float* __restrict__ Wr1,
                                            const float* __restrict__ br1,
                                            const float* __restrict__ Wr2,
                                            const float* __restrict__ br2,
                                            float* __restrict__ out) {
  int t = threadIdx.x;
  if (t >= NGRAPH) return;
  float cnt = fmaxf(gcnt[t], 1.f);
  float g0 = gsum[t * 3 + 0] / cnt;
  float g1 = gsum[t * 3 + 1] / cnt;
  float g2 = gsum[t * 3 + 2] / cnt;
  float o0 = br2[0], o1 = br2[1], o2 = br2[2];
  for (int j = 0; j < 64; ++j) {
    float hj = g0 * Wr1[j] + g1 * Wr1[64 + j] + g2 * Wr1[128 + j] + br1[j];
    hj = fmaxf(hj, 0.f);
    o0 = fmaf(hj, Wr2[j * 3 + 0], o0);
    o1 = fmaf(hj, Wr2[j * 3 + 1], o1);
    o2 = fmaf(hj, Wr2[j * 3 + 2], o2);
  }
  out[t * 3 + 0] = o0;
  out[t * 3 + 1] = o1;
  out[t * 3 + 2] = o2;
}

// ---------------------------------------------------------------------------
extern "C" void kernel_launch(void* const* d_in, const int* in_sizes, int n_in,
                              void* d_out, int out_size, void* d_ws, size_t ws_size,
                              hipStream_t stream) {
  const float* x    = (const float*)d_in[0];
  const int*   ei   = (const int*)d_in[1];
  const int*   batch= (const int*)d_in[2];
  const float* W1l  = (const float*)d_in[3];
  const float* W1r  = (const float*)d_in[4];
  const float* att1 = (const float*)d_in[5];
  const float* b1   = (const float*)d_in[6];
  const float* W2l  = (const float*)d_in[7];
  const float* W2r  = (const float*)d_in[8];
  const float* att2 = (const float*)d_in[9];
  const float* b2   = (const float*)d_in[10];
  const float* Wr1  = (const float*)d_in[11];
  const float* br1  = (const float*)d_in[12];
  const float* Wr2  = (const float*)d_in[13];
  const float* br2  = (const float*)d_in[14];
  float* out = (float*)d_out;

  const int N  = in_sizes[0] / 128;
  const int E  = in_sizes[1] / 2;
  const int Et = E + N;
  const int NB = (N + 1023) / 1024;  // scan blocks (<=64)

  char* p = (char*)d_ws;
  auto alloc = [&](size_t bytes) -> char* {
    char* r = p;
    p += (bytes + 255) & ~(size_t)255;
    return r;
  };
  unsigned short* xl1 = (unsigned short*)alloc((size_t)N * 128 * 2);  // bf16
  float*    xr1    = (float*)alloc((size_t)N * 128 * 4);
  int*      row_ptr= (int*)alloc((size_t)(N + 1) * 4);
  int*      csr_src= (int*)alloc((size_t)Et * 4);
  int*      rank   = (int*)alloc((size_t)Et * 4);
  int*      bsum   = (int*)alloc(64 * 4);
  // zero-init group (one memset): deg | gsum | gcnt
  char*     z0     = p;
  int*      deg    = (int*)alloc((size_t)N * 4);
  float*    gsum   = (float*)alloc(NGRAPH * 3 * 4);
  float*    gcnt   = (float*)alloc(NGRAPH * 4);
  size_t    zbytes = (size_t)(p - z0);
  float*    xl2    = (float*)alloc((size_t)N * 4 * 4);
  float*    xr2    = (float*)alloc((size_t)N * 4 * 4);
  // R14: split-bf16 operands for the matrix-core GEMM
  unsigned short* xh  = (unsigned short*)alloc((size_t)N * 128 * 2);
  unsigned short* xlo = (unsigned short*)alloc((size_t)N * 128 * 2);
  unsigned short* wth = (unsigned short*)alloc((size_t)256 * 128 * 2);
  unsigned short* wtl = (unsigned short*)alloc((size_t)256 * 128 * 2);

  hipMemsetAsync(z0, 0, zbytes, stream);
  hipLaunchKernelGGL(k_deg, dim3((Et + 255) / 256), dim3(256), 0, stream,
                     ei, E, Et, deg, rank);
  hipLaunchKernelGGL(k_scan_part, dim3(NB), dim3(256), 0, stream, deg, bsum, N);
  hipLaunchKernelGGL(k_scan_top, dim3(1), dim3(64), 0, stream, bsum, NB);
  hipLaunchKernelGGL(k_scan_write, dim3(NB), dim3(256), 0, stream,
                     deg, bsum, row_ptr, N);
  hipLaunchKernelGGL(k_fill, dim3((Et + 255) / 256), dim3(256), 0, stream,
                     ei, E, Et, row_ptr, rank, csr_src);
  const int total_x = N * 128;
  const int xblk = (total_x + 2047) / 2048;
  const int wblk = (256 * 128 + 255) / 256;
  hipLaunchKernelGGL(k_cvt, dim3(xblk + wblk), dim3(256), 0, stream,
                     x, W1l, W1r, xh, xlo, wth, wtl, total_x, xblk);
  hipLaunchKernelGGL(k_gmfma, dim3((N + 63) / 64), dim3(256), 0, stream,
                     xh, xlo, wth, wtl, xl1, xr1, N);
  int waves1 = (N + 1) / 2;
  hipLaunchKernelGGL(k_fused1, dim3((waves1 * 64 + 255) / 256), dim3(256), 0, stream,
                     xl1, xr1, row_ptr, csr_src, att1, b1, W2l, W2r, xl2, xr2, N);
  hipLaunchKernelGGL(k_fused2, dim3((N * 16 + 255) / 256), dim3(256), 0, stream,
                     xl2, xr2, row_ptr, csr_src, att2, b2, batch, gsum, gcnt, N);
  hipLaunchKernelGGL(k_mlp, dim3(1), dim3(64), 0, stream,
                     gsum, gcnt, Wr1, br1, Wr2, br2, out);
}

// Round 3
// 258.807 us; speedup vs baseline: 1.0888x; 1.0722x over previous
//
#include <hip/hip_runtime.h>

// ---------------------------------------------------------------------------
// GATv2 (2 layers) + mean-pool + MLP for MI355X.
// N=50000 nodes, E=800000 edges (+N self loops), IN=128, HID=64, HEADS=2,
// OUT=3, 64 graphs. Output: [64,3] float32.
// R1: k_agg2 pool atomic storm fixed (LDS pre-reduction). 1128 -> 803 us.
// R2: CSR + per-node online softmax; edge phases fused.   803 -> 515 us.
// R3: fused1 2-edge ILP + reg src cache + W2-proj fused.   515 -> 394 us.
// R4: fused1 2 nodes/wave + 4-edge ILP + batched softmax.  394 -> 368 us.
// R5: gemm 128x128 reg-blocked (LDS 72KB->16KB).            368 -> 343 us.
// R6: DPP rotate-reduce + exp2 domain; gemm 64x128/4x8.     343 -> 337 us.
// R7: 8-edge unroll flat. R8-R10: degree-sort detour regressed; reverted.
// R11: 3-phase parallel scan (single-block scan was 100us!). 422 -> 329 us.
// R12: xl1 message table bf16 (gather 512->256B/edge).       329 -> 326 us.
// R13: k_fill atomic-free; gemm merged (x@W1l AND x@W1r).    326 -> 282 us.
// R14: GEMM to matrix cores via split-bf16 (x=xh+xl, W=Wh+Wl; hh+hl+lh
//      MFMA passes = fp32-class accuracy). Only 282 -> 277: the LDS-free
//      frag loads were 16-segment scatters, L2-latency-bound (~45 us).
// R15: frag-order PRE-PACK. k_cvt emits xh/xl and Wh/Wl already laid out in
//      mfma_16x16x32_bf16 fragment order ((rowblk,kc,lane)*8+j), so every
//      k_gmfma fragment load is one coalesced 64-lane x 16B = 1KB burst.
//      Tile 32 rows/block (1563 blocks, ~6 waves/SIMD). Math order identical
//      to R14 -> bit-identical output.
// R16: resubmit of R15 — round 2 bench was an infra failure (container
//      acquisition failed twice; kernel never ran). Code audit found no OOB
//      or alignment hazard; workspace footprint matches R14's passing run.
// ---------------------------------------------------------------------------

#define NGRAPH 64
#define LOG2E 1.4426950408889634f

// v_mov_dpp row_ror:k (16-lane rows). Valid reduce permutation for
// commutative ops; leaves every lane of the row with the full result.
#define DPP_ROR(C, x) \
  __int_as_float(__builtin_amdgcn_update_dpp(0, __float_as_int(x), (0x120 | C), 0xF, 0xF, false))

__device__ __forceinline__ float rowsum16(float v) {
  v += DPP_ROR(8, v);
  v += DPP_ROR(4, v);
  v += DPP_ROR(2, v);
  v += DPP_ROR(1, v);
  return v;
}

__device__ __forceinline__ unsigned bf16rne(float f) {
  unsigned u = __float_as_uint(f);
  return (u + 0x7FFFu + ((u >> 16) & 1u)) >> 16;
}

typedef __attribute__((ext_vector_type(8))) short bf16x8;
typedef __attribute__((ext_vector_type(4))) float f32x4;

// ---------------------------------------------------------------------------
// R13: the atomic's return value IS this edge's rank among its dst's edges.
__global__ void k_deg(const int* __restrict__ ei, int E, int Et,
                      int* __restrict__ deg, int* __restrict__ rank) {
  int e = blockIdx.x * blockDim.x + threadIdx.x;
  if (e >= Et) return;
  int d = (e < E) ? ei[E + e] : (e - E);  // dst only
  rank[e] = atomicAdd(&deg[d], 1);        // coalesced store of the rank
}

// ---------------------------------------------------------------------------
// 3-phase parallel exclusive scan of deg[0..n) -> row_ptr[0..n].
__global__ __launch_bounds__(256) void k_scan_part(const int* __restrict__ deg,
                                                   int* __restrict__ bsum, int n) {
  __shared__ int sd[256];
  int t = threadIdx.x;
  int i = blockIdx.x * 1024 + t * 4;
  int s = 0;
  if (i + 4 <= n) {
    int4 d = *(const int4*)&deg[i];
    s = d.x + d.y + d.z + d.w;
  } else {
    for (int j = i; j < min(i + 4, n); ++j) s += deg[j];
  }
  sd[t] = s;
  __syncthreads();
  for (int off = 128; off; off >>= 1) {
    if (t < off) sd[t] += sd[t + off];
    __syncthreads();
  }
  if (t == 0) bsum[blockIdx.x] = sd[0];
}

__global__ __launch_bounds__(64) void k_scan_top(int* __restrict__ bsum, int nb) {
  __shared__ int s[64];
  int t = threadIdx.x;
  s[t] = (t < nb) ? bsum[t] : 0;
  __syncthreads();
  int acc = 0;
  for (int j = 0; j < t; ++j) acc += s[j];
  if (t < nb) bsum[t] = acc;
}

__global__ __launch_bounds__(256) void k_scan_write(const int* __restrict__ deg,
                                                    const int* __restrict__ bsum,
                                                    int* __restrict__ row_ptr, int n) {
  __shared__ int sd[256];
  int t = threadIdx.x;
  int i = blockIdx.x * 1024 + t * 4;
  int4 d = make_int4(0, 0, 0, 0);
  bool full = (i + 4 <= n);
  if (full) d = *(const int4*)&deg[i];
  else {
    if (i + 0 < n) d.x = deg[i + 0];
    if (i + 1 < n) d.y = deg[i + 1];
    if (i + 2 < n) d.z = deg[i + 2];
    if (i + 3 < n) d.w = deg[i + 3];
  }
  int s = d.x + d.y + d.z + d.w;
  sd[t] = s;
  __syncthreads();
  for (int off = 1; off < 256; off <<= 1) {  // Hillis-Steele inclusive
    int v = (t >= off) ? sd[t - off] : 0;
    __syncthreads();
    sd[t] += v;
    __syncthreads();
  }
  int ex = sd[t] - s + bsum[blockIdx.x];
  int4 r;
  r.x = ex;
  r.y = ex + d.x;
  r.z = r.y + d.y;
  r.w = r.z + d.z;
  if (full) {
    *(int4*)&row_ptr[i] = r;
    if (i + 4 == n) row_ptr[n] = r.w + d.w;
  } else if (i < n) {
    int run = ex;
    int vals[4] = {d.x, d.y, d.z, d.w};
    for (int j = 0; j < 4 && i + j < n; ++j) {
      row_ptr[i + j] = run;
      run += vals[j];
    }
    if (i <= n && i + 4 > n) row_ptr[n] = run;
  }
}

// R13: no atomic — slot is row_ptr[d] + precomputed rank.
__global__ void k_fill(const int* __restrict__ ei, int E, int Et,
                       const int* __restrict__ row_ptr,
                       const int* __restrict__ rank,
                       int* __restrict__ csr_src) {
  int e = blockIdx.x * blockDim.x + threadIdx.x;
  if (e >= Et) return;
  int s, d;
  if (e < E) { s = ei[e]; d = ei[E + e]; }
  else       { s = e - E; d = s; }
  csr_src[row_ptr[d] + rank[e]] = s;
}

// ---------------------------------------------------------------------------
// R15 prep: split-bf16 decomposition emitted in MFMA FRAGMENT ORDER.
// Pack layout for a [rows][K=128] matrix: element (rowblk rb, kchunk kc,
// lane l, j) holds M[rb*16 + (l&15)][kc*32 + (l>>4)*8 + j] at linear index
// ((rb*4+kc)*64 + l)*8 + j. A 64-lane fragment load is then 1KB contiguous.
//   blocks [0, RB):     x -> xhp (bf16 hi) / xlp (bf16 of residual); rows >= n
//                       zero-filled so k_gmfma loads are never OOB.
//   blocks [RB, RB+16): W1l|W1r (cols 0..127 = W1l, 128..255 = W1r) -> whp/wlp.
__global__ __launch_bounds__(256) void k_cvt(const float* __restrict__ x,
                                             const float* __restrict__ W1l,
                                             const float* __restrict__ W1r,
                                             unsigned short* __restrict__ xhp,
                                             unsigned short* __restrict__ xlp,
                                             unsigned short* __restrict__ whp,
                                             unsigned short* __restrict__ wlp,
                                             int n, int RB) {
  int t = threadIdx.x;
  int kc = t >> 6;
  int l = t & 63;
  int lr = l & 15;
  int k0 = kc * 32 + (l >> 4) * 8;
  int b = blockIdx.x;
  float f[8];
  if (b < RB) {
    int row = b * 16 + lr;
    if (row < n) {
      float4 a = *(const float4*)&x[(size_t)row * 128 + k0];
      float4 c = *(const float4*)&x[(size_t)row * 128 + k0 + 4];
      f[0] = a.x; f[1] = a.y; f[2] = a.z; f[3] = a.w;
      f[4] = c.x; f[5] = c.y; f[6] = c.z; f[7] = c.w;
    } else {
#pragma unroll
      for (int j = 0; j < 8; ++j) f[j] = 0.f;
    }
  } else {
    int col = (b - RB) * 16 + lr;
#pragma unroll
    for (int j = 0; j < 8; ++j)
      f[j] = (col < 128) ? W1l[(size_t)(k0 + j) * 128 + col]
                         : W1r[(size_t)(k0 + j) * 128 + (col - 128)];
  }
  unsigned hv[8], lv[8];
#pragma unroll
  for (int j = 0; j < 8; ++j) {
    hv[j] = bf16rne(f[j]);
    float r = f[j] - __uint_as_float(hv[j] << 16);
    lv[j] = bf16rne(r);
  }
  uint4 ph, pl;
  ph.x = hv[0] | (hv[1] << 16); ph.y = hv[2] | (hv[3] << 16);
  ph.z = hv[4] | (hv[5] << 16); ph.w = hv[6] | (hv[7] << 16);
  pl.x = lv[0] | (lv[1] << 16); pl.y = lv[2] | (lv[3] << 16);
  pl.z = lv[4] | (lv[5] << 16); pl.w = lv[6] | (lv[7] << 16);
  if (b < RB) {
    size_t slot = (((size_t)b * 4 + kc) * 64 + l) * 8;
    *(uint4*)&xhp[slot] = ph;
    *(uint4*)&xlp[slot] = pl;
  } else {
    size_t slot = (((size_t)(b - RB) * 4 + kc) * 64 + l) * 8;
    *(uint4*)&whp[slot] = ph;
    *(uint4*)&wlp[slot] = pl;
  }
}

// ---------------------------------------------------------------------------
// R15 GEMM on matrix cores, frag-pack operands. Per block: 32 rows x 256
// cols, 4 waves; wave w owns cols [w*64, w*64+64). Waves 0-1 -> xl1 = x@W1l
// (bf16), waves 2-3 -> xr1 = x@W1r (fp32). Every fragment load is one
// coalesced 1KB burst (64 lanes x 16B). 3 MFMA passes per frag pair:
// xh*Wh + xh*Wl + xl*Wh — same order as R14, bit-identical results.
// mfma_f32_16x16x32_bf16 layouts (learn_hip m89/m91-verified):
//   A: row = lane&15, k = (lane>>4)*8 + j
//   B: col = lane&15, k = (lane>>4)*8 + j
//   D: col = lane&15, row = (lane>>4)*4 + reg
__global__ __launch_bounds__(256) void k_gmfma(const unsigned short* __restrict__ xhp,
                                               const unsigned short* __restrict__ xlp,
                                               const unsigned short* __restrict__ whp,
                                               const unsigned short* __restrict__ wlp,
                                               unsigned short* __restrict__ outl,
                                               float* __restrict__ outr, int n) {
  int w = threadIdx.x >> 6;
  int lane = threadIdx.x & 63;
  int lr = lane & 15;
  int r0 = blockIdx.x * 32;
  int rb0 = blockIdx.x * 2;

  f32x4 acc[2][4] = {};

#pragma unroll
  for (int kc = 0; kc < 4; ++kc) {
    bf16x8 ah[2], al[2], bh[4], bl[4];
#pragma unroll
    for (int m = 0; m < 2; ++m) {
      size_t slot = (((size_t)(rb0 + m) * 4 + kc) * 64 + lane) * 8;
      ah[m] = *(const bf16x8*)&xhp[slot];
      al[m] = *(const bf16x8*)&xlp[slot];
    }
#pragma unroll
    for (int f = 0; f < 4; ++f) {
      size_t slot = (((size_t)(w * 4 + f) * 4 + kc) * 64 + lane) * 8;
      bh[f] = *(const bf16x8*)&whp[slot];
      bl[f] = *(const bf16x8*)&wlp[slot];
    }
#pragma unroll
    for (int m = 0; m < 2; ++m)
#pragma unroll
      for (int f = 0; f < 4; ++f) {
        acc[m][f] = __builtin_amdgcn_mfma_f32_16x16x32_bf16(ah[m], bh[f], acc[m][f], 0, 0, 0);
        acc[m][f] = __builtin_amdgcn_mfma_f32_16x16x32_bf16(ah[m], bl[f], acc[m][f], 0, 0, 0);
        acc[m][f] = __builtin_amdgcn_mfma_f32_16x16x32_bf16(al[m], bh[f], acc[m][f], 0, 0, 0);
      }
  }

  int rbase = (lane >> 4) * 4;
  if (w < 2) {
#pragma unroll
    for (int m = 0; m < 2; ++m)
#pragma unroll
      for (int f = 0; f < 4; ++f) {
        int col = w * 64 + f * 16 + lr;
#pragma unroll
        for (int i = 0; i < 4; ++i) {
          int row = r0 + m * 16 + rbase + i;
          if (row < n)
            outl[(size_t)row * 128 + col] = (unsigned short)bf16rne(acc[m][f][i]);
        }
      }
  } else {
#pragma unroll
    for (int m = 0; m < 2; ++m)
#pragma unroll
      for (int f = 0; f < 4; ++f) {
        int col = (w - 2) * 64 + f * 16 + lr;
#pragma unroll
        for (int i = 0; i < 4; ++i) {
          int row = r0 + m * 16 + rbase + i;
          if (row < n)
            outr[(size_t)row * 128 + col] = acc[m][f][i];
        }
      }
  }
}

// ---------------------------------------------------------------------------
// fused layer-1 edge phase + layer-2 input projection.
// TWO nodes per wave: lanes 0-31 = node 2w, 32-63 = node 2w+1. Lane holds 4
// channels; 16-lane head groups = DPP rows. 4 edges/iter: clamp-free main
// loop to mindeg, clamped+masked tail to maxdeg. xl gathered as BF16x4
// (uint2, 8B/lane = 256B/row) and unpacked with shift/mask; acc fp32.
__global__ __launch_bounds__(256) void k_fused1(const unsigned short* __restrict__ xl,
                                                const float* __restrict__ xr,
                                                const int* __restrict__ row_ptr,
                                                const int* __restrict__ csr_src,
                                                const float* __restrict__ att1,
                                                const float* __restrict__ b1,
                                                const float* __restrict__ W2l,
                                                const float* __restrict__ W2r,
                                                float* __restrict__ xl2,
                                                float* __restrict__ xr2, int n) {
  int wid  = (blockIdx.x * 256 + threadIdx.x) >> 6;
  int lane = threadIdx.x & 63;
  int sub  = lane & 31;
  int node = min(wid * 2 + (lane >> 5), n - 1);  // dup of last node is benign
  int ch = sub * 4;
  const char* xlb = (const char*)xl;
  unsigned chb = (unsigned)sub * 8u;  // byte offset within 256B bf16 row
  float4 xrv = *(const float4*)&xr[(size_t)node * 128 + ch];
  float4 atv = *(const float4*)&att1[ch];
  atv.x *= LOG2E; atv.y *= LOG2E; atv.z *= LOG2E; atv.w *= LOG2E;
  int s0 = row_ptr[node];
  int deg = row_ptr[node + 1] - s0;  // >=1 (self-loop)
  int odeg = __shfl_xor(deg, 32);
  int mindeg = min(deg, odeg);  // wave-uniform
  int maxdeg = max(deg, odeg);  // wave-uniform
  const int* sp = csr_src + s0;

  float m = -1e30f, l = 0.f;
  float4 acc = make_float4(0.f, 0.f, 0.f, 0.f);

  float t0, t1, t2, t3;
#define UNPACK(dst, q)                                                  \
    dst.x = __uint_as_float(q.x << 16);                                 \
    dst.y = __uint_as_float(q.x & 0xFFFF0000u);                         \
    dst.z = __uint_as_float(q.y << 16);                                 \
    dst.w = __uint_as_float(q.y & 0xFFFF0000u);
#define LOGIT(p, v)                                                     \
    t0 = v.x + xrv.x; t0 = fmaxf(t0, 0.2f * t0);                        \
    t1 = v.y + xrv.y; t1 = fmaxf(t1, 0.2f * t1);                        \
    t2 = v.z + xrv.z; t2 = fmaxf(t2, 0.2f * t2);                        \
    t3 = v.w + xrv.w; t3 = fmaxf(t3, 0.2f * t3);                        \
    p = fmaf(t3, atv.w, fmaf(t2, atv.z, fmaf(t1, atv.y, t0 * atv.x)));

#define BODY(CLAMPED)                                                   \
  {                                                                     \
    int sA, sB, sC, sD;                                                 \
    if (CLAMPED) {                                                      \
      int dm1 = deg - 1;                                                \
      sA = sp[min(e + 0, dm1)];                                         \
      sB = sp[min(e + 1, dm1)];                                         \
      sC = sp[min(e + 2, dm1)];                                         \
      sD = sp[min(e + 3, dm1)];                                         \
    } else {                                                            \
      sA = sp[e + 0]; sB = sp[e + 1]; sC = sp[e + 2]; sD = sp[e + 3];   \
    }                                                                   \
    uint2 qa = *(const uint2*)(xlb + (((unsigned)sA << 8) + chb));      \
    uint2 qb = *(const uint2*)(xlb + (((unsigned)sB << 8) + chb));      \
    uint2 qc = *(const uint2*)(xlb + (((unsigned)sC << 8) + chb));      \
    uint2 qd = *(const uint2*)(xlb + (((unsigned)sD << 8) + chb));      \
    float4 xa, xb, xc, xd;                                              \
    UNPACK(xa, qa) UNPACK(xb, qb) UNPACK(xc, qc) UNPACK(xd, qd)         \
    float pa, pb, pc, pd;                                               \
    LOGIT(pa, xa) LOGIT(pb, xb) LOGIT(pc, xc) LOGIT(pd, xd)             \
    pa = rowsum16(pa);                                                  \
    pb = rowsum16(pb);                                                  \
    pc = rowsum16(pc);                                                  \
    pd = rowsum16(pd);                                                  \
    if (CLAMPED) {                                                      \
      pa = (e + 0 < deg) ? pa : -1e30f;                                 \
      pb = (e + 1 < deg) ? pb : -1e30f;                                 \
      pc = (e + 2 < deg) ? pc : -1e30f;                                 \
      pd = (e + 3 < deg) ? pd : -1e30f;                                 \
    }                                                                   \
    float mn = fmaxf(m, fmaxf(fmaxf(pa, pb), fmaxf(pc, pd)));           \
    float sc = exp2f(m - mn);                                           \
    float wa = exp2f(pa - mn);                                          \
    float wb = exp2f(pb - mn);                                          \
    float wc = exp2f(pc - mn);                                          \
    float wd = exp2f(pd - mn);                                          \
    acc.x = fmaf(wd, xd.x, fmaf(wc, xc.x, fmaf(wb, xb.x, fmaf(wa, xa.x, acc.x * sc)))); \
    acc.y = fmaf(wd, xd.y, fmaf(wc, xc.y, fmaf(wb, xb.y, fmaf(wa, xa.y, acc.y * sc)))); \
    acc.z = fmaf(wd, xd.z, fmaf(wc, xc.z, fmaf(wb, xb.z, fmaf(wa, xa.z, acc.z * sc)))); \
    acc.w = fmaf(wd, xd.w, fmaf(wc, xc.w, fmaf(wb, xb.w, fmaf(wa, xa.w, acc.w * sc)))); \
    l = fmaf(l, sc, wa + wb + wc + wd);                                 \
    m = mn;                                                             \
  }

  int e = 0;
  for (; e + 4 <= mindeg; e += 4) BODY(false)
  for (; e < maxdeg; e += 4) BODY(true)
#undef BODY
#undef LOGIT
#undef UNPACK

  float inv = 1.f / (l + 1e-16f);
  float4 b1v = *(const float4*)&b1[ch];
  float4 h;
  h.x = acc.x * inv + b1v.x; h.x = h.x > 0.f ? h.x : expm1f(h.x);
  h.y = acc.y * inv + b1v.y; h.y = h.y > 0.f ? h.y : expm1f(h.y);
  h.z = acc.z * inv + b1v.z; h.z = h.z > 0.f ? h.z : expm1f(h.z);
  h.w = acc.w * inv + b1v.w; h.w = h.w > 0.f ? h.w : expm1f(h.w);

  float4 u0 = *(const float4*)&W2l[ch * 3 + 0];
  float4 u1 = *(const float4*)&W2l[ch * 3 + 4];
  float4 u2 = *(const float4*)&W2l[ch * 3 + 8];
  float al0 = fmaf(h.w, u2.y, fmaf(h.z, u1.z, fmaf(h.y, u0.w, h.x * u0.x)));
  float al1 = fmaf(h.w, u2.z, fmaf(h.z, u1.w, fmaf(h.y, u1.x, h.x * u0.y)));
  float al2 = fmaf(h.w, u2.w, fmaf(h.z, u2.x, fmaf(h.y, u1.y, h.x * u0.z)));
  float4 v0 = *(const float4*)&W2r[ch * 3 + 0];
  float4 v1 = *(const float4*)&W2r[ch * 3 + 4];
  float4 v2 = *(const float4*)&W2r[ch * 3 + 8];
  float ar0 = fmaf(h.w, v2.y, fmaf(h.z, v1.z, fmaf(h.y, v0.w, h.x * v0.x)));
  float ar1 = fmaf(h.w, v2.z, fmaf(h.z, v1.w, fmaf(h.y, v1.x, h.x * v0.y)));
  float ar2 = fmaf(h.w, v2.w, fmaf(h.z, v2.x, fmaf(h.y, v1.y, h.x * v0.z)));
#pragma unroll
  for (int off = 1; off < 32; off <<= 1) {
    al0 += __shfl_xor(al0, off); al1 += __shfl_xor(al1, off);
    al2 += __shfl_xor(al2, off); ar0 += __shfl_xor(ar0, off);
    ar1 += __shfl_xor(ar1, off); ar2 += __shfl_xor(ar2, off);
  }
  if (sub == 0 && wid * 2 + (lane >> 5) < n) {
    *(float4*)&xl2[node * 4] = make_float4(al0, al1, al2, 0.f);
    *(float4*)&xr2[node * 4] = make_float4(ar0, ar1, ar2, 0.f);
  }
}

// ---------------------------------------------------------------------------
// fused layer-2 edge phase + mean-pool. 16 lanes per node (= one DPP row);
// per-lane online softmax (exp2 domain) over a 16-stride slice, DPP rotate
// merge of (m,l,acc3) states. Pool pre-reduced in LDS.
__global__ __launch_bounds__(256) void k_fused2(const float* __restrict__ xl2,
                                                const float* __restrict__ xr2,
                                                const int* __restrict__ row_ptr,
                                                const int* __restrict__ csr_src,
                                                const float* __restrict__ att2,
                                                const float* __restrict__ b2,
                                                const int* __restrict__ batch,
                                                float* __restrict__ gsum,
                                                float* __restrict__ gcnt, int n) {
  __shared__ float ls[NGRAPH * 3];
  __shared__ float lc[NGRAPH];
  int t = threadIdx.x;
  for (int i = t; i < NGRAPH * 3; i += 256) ls[i] = 0.f;
  for (int i = t; i < NGRAPH; i += 256) lc[i] = 0.f;
  __syncthreads();

  int node = (blockIdx.x * 256 + t) >> 4;  // 16 nodes per block
  int lane = t & 15;
  if (node < n) {
    float4 xrv = *(const float4*)&xr2[node * 4];
    float c0 = att2[0] * LOG2E, c1 = att2[1] * LOG2E, c2 = att2[2] * LOG2E;
    int s0 = row_ptr[node], s1 = row_ptr[node + 1];
    float m = -1e30f, l = 0.f, a0 = 0.f, a1 = 0.f, a2 = 0.f;
    for (int slot = s0 + lane; slot < s1; slot += 16) {
      int s = csr_src[slot];
      float4 xlv = *(const float4*)&xl2[s * 4];
      float t0 = xlv.x + xrv.x; t0 = fmaxf(t0, 0.2f * t0);
      float t1 = xlv.y + xrv.y; t1 = fmaxf(t1, 0.2f * t1);
      float t2 = xlv.z + xrv.z; t2 = fmaxf(t2, 0.2f * t2);
      float p = fmaf(t2, c2, fmaf(t1, c1, t0 * c0));
      float mn = fmaxf(m, p);
      float sc = exp2f(m - mn);
      float w  = exp2f(p - mn);
      a0 = a0 * sc + w * xlv.x;
      a1 = a1 * sc + w * xlv.y;
      a2 = a2 * sc + w * xlv.z;
      l = l * sc + w;
      m = mn;
    }
#define MERGE(C)                                                        \
    {                                                                   \
      float m2 = DPP_ROR(C, m);                                         \
      float l2 = DPP_ROR(C, l);                                         \
      float b0 = DPP_ROR(C, a0);                                        \
      float b1v = DPP_ROR(C, a1);                                       \
      float b2v = DPP_ROR(C, a2);                                       \
      float mn = fmaxf(m, m2);                                          \
      float sA = exp2f(m - mn);                                         \
      float sB = exp2f(m2 - mn);                                        \
      a0 = a0 * sA + b0 * sB;                                           \
      a1 = a1 * sA + b1v * sB;                                          \
      a2 = a2 * sA + b2v * sB;                                          \
      l = l * sA + l2 * sB;                                             \
      m = mn;                                                           \
    }
    MERGE(8) MERGE(4) MERGE(2) MERGE(1)
#undef MERGE
    if (lane == 0) {
      float inv = 1.f / (l + 1e-16f);
      float o0 = a0 * inv + b2[0];
      float o1 = a1 * inv + b2[1];
      float o2 = a2 * inv + b2[2];
      int b = batch[node];
      atomicAdd(&ls[b * 3 + 0], o0);
      atomicAdd(&ls[b * 3 + 1], o1);
      atomicAdd(&ls[b * 3 + 2], o2);
      atomicAdd(&lc[b], 1.f);
    }
  }
  __syncthreads();
  for (int i = t; i < NGRAPH * 3; i += 256)
    if (ls[i] != 0.f) atomicAdd(&gsum[i], ls[i]);
  for (int i = t; i < NGRAPH; i += 256)
    if (lc[i] != 0.f) atomicAdd(&gcnt[i], lc[i]);
}

// 1 block, 64 threads: per-graph mean + 2-layer MLP
__global__ __launch_bounds__(64) void k_mlp(const float* __restrict__ gsum,
                                            const float* __restrict__ gcnt,
                                            const float* __restrict__ Wr1,
                                            const float* __restrict__ br1,
                                            const float* __restrict__ Wr2,
                                            const float* __restrict__ br2,
                                            float* __restrict__ out) {
  int t = threadIdx.x;
  if (t >= NGRAPH) return;
  float cnt = fmaxf(gcnt[t], 1.f);
  float g0 = gsum[t * 3 + 0] / cnt;
  float g1 = gsum[t * 3 + 1] / cnt;
  float g2 = gsum[t * 3 + 2] / cnt;
  float o0 = br2[0], o1 = br2[1], o2 = br2[2];
  for (int j = 0; j < 64; ++j) {
    float hj = g0 * Wr1[j] + g1 * Wr1[64 + j] + g2 * Wr1[128 + j] + br1[j];
    hj = fmaxf(hj, 0.f);
    o0 = fmaf(hj, Wr2[j * 3 + 0], o0);
    o1 = fmaf(hj, Wr2[j * 3 + 1], o1);
    o2 = fmaf(hj, Wr2[j * 3 + 2], o2);
  }
  out[t * 3 + 0] = o0;
  out[t * 3 + 1] = o1;
  out[t * 3 + 2] = o2;
}

// ---------------------------------------------------------------------------
extern "C" void kernel_launch(void* const* d_in, const int* in_sizes, int n_in,
                              void* d_out, int out_size, void* d_ws, size_t ws_size,
                              hipStream_t stream) {
  const float* x    = (const float*)d_in[0];
  const int*   ei   = (const int*)d_in[1];
  const int*   batch= (const int*)d_in[2];
  const float* W1l  = (const float*)d_in[3];
  const float* W1r  = (const float*)d_in[4];
  const float* att1 = (const float*)d_in[5];
  const float* b1   = (const float*)d_in[6];
  const float* W2l  = (const float*)d_in[7];
  const float* W2r  = (const float*)d_in[8];
  const float* att2 = (const float*)d_in[9];
  const float* b2   = (const float*)d_in[10];
  const float* Wr1  = (const float*)d_in[11];
  const float* br1  = (const float*)d_in[12];
  const float* Wr2  = (const float*)d_in[13];
  const float* br2  = (const float*)d_in[14];
  float* out = (float*)d_out;

  const int N  = in_sizes[0] / 128;
  const int E  = in_sizes[1] / 2;
  const int Et = E + N;
  const int NB = (N + 1023) / 1024;  // scan blocks (<=64)
  const int NB32 = (N + 31) / 32;    // gmfma blocks
  const int RB = NB32 * 2;           // padded 16-row blocks in the A-pack

  char* p = (char*)d_ws;
  auto alloc = [&](size_t bytes) -> char* {
    char* r = p;
    p += (bytes + 255) & ~(size_t)255;
    return r;
  };
  unsigned short* xl1 = (unsigned short*)alloc((size_t)N * 128 * 2);  // bf16
  float*    xr1    = (float*)alloc((size_t)N * 128 * 4);
  int*      row_ptr= (int*)alloc((size_t)(N + 1) * 4);
  int*      csr_src= (int*)alloc((size_t)Et * 4);
  int*      rank   = (int*)alloc((size_t)Et * 4);
  int*      bsum   = (int*)alloc(64 * 4);
  // zero-init group (one memset): deg | gsum | gcnt
  char*     z0     = p;
  int*      deg    = (int*)alloc((size_t)N * 4);
  float*    gsum   = (float*)alloc(NGRAPH * 3 * 4);
  float*    gcnt   = (float*)alloc(NGRAPH * 4);
  size_t    zbytes = (size_t)(p - z0);
  float*    xl2    = (float*)alloc((size_t)N * 4 * 4);
  float*    xr2    = (float*)alloc((size_t)N * 4 * 4);
  // R15: frag-packed split-bf16 operands for the matrix-core GEMM
  unsigned short* xhp = (unsigned short*)alloc((size_t)RB * 2048 * 2);
  unsigned short* xlp = (unsigned short*)alloc((size_t)RB * 2048 * 2);
  unsigned short* whp = (unsigned short*)alloc((size_t)16 * 2048 * 2);
  unsigned short* wlp = (unsigned short*)alloc((size_t)16 * 2048 * 2);

  hipMemsetAsync(z0, 0, zbytes, stream);
  hipLaunchKernelGGL(k_deg, dim3((Et + 255) / 256), dim3(256), 0, stream,
                     ei, E, Et, deg, rank);
  hipLaunchKernelGGL(k_scan_part, dim3(NB), dim3(256), 0, stream, deg, bsum, N);
  hipLaunchKernelGGL(k_scan_top, dim3(1), dim3(64), 0, stream, bsum, NB);
  hipLaunchKernelGGL(k_scan_write, dim3(NB), dim3(256), 0, stream,
                     deg, bsum, row_ptr, N);
  hipLaunchKernelGGL(k_fill, dim3((Et + 255) / 256), dim3(256), 0, stream,
                     ei, E, Et, row_ptr, rank, csr_src);
  hipLaunchKernelGGL(k_cvt, dim3(RB + 16), dim3(256), 0, stream,
                     x, W1l, W1r, xhp, xlp, whp, wlp, N, RB);
  hipLaunchKernelGGL(k_gmfma, dim3(NB32), dim3(256), 0, stream,
                     xhp, xlp, whp, wlp, xl1, xr1, N);
  int waves1 = (N + 1) / 2;
  hipLaunchKernelGGL(k_fused1, dim3((waves1 * 64 + 255) / 256), dim3(256), 0, stream,
                     xl1, xr1, row_ptr, csr_src, att1, b1, W2l, W2r, xl2, xr2, N);
  hipLaunchKernelGGL(k_fused2, dim3((N * 16 + 255) / 256), dim3(256), 0, stream,
                     xl2, xr2, row_ptr, csr_src, att2, b2, batch, gsum, gcnt, N);
  hipLaunchKernelGGL(k_mlp, dim3(1), dim3(64), 0, stream,
                     gsum, gcnt, Wr1, br1, Wr2, br2, out);
}

// Round 4
// 245.382 us; speedup vs baseline: 1.1483x; 1.0547x over previous
//
#include <hip/hip_runtime.h>

// ---------------------------------------------------------------------------
// GATv2 (2 layers) + mean-pool + MLP for MI355X.
// N=50000 nodes, E=800000 edges (+N self loops), IN=128, HID=64, HEADS=2,
// OUT=3, 64 graphs. Output: [64,3] float32.
// R1: k_agg2 pool atomic storm fixed (LDS pre-reduction). 1128 -> 803 us.
// R2: CSR + per-node online softmax; edge phases fused.   803 -> 515 us.
// R3: fused1 2-edge ILP + reg src cache + W2-proj fused.   515 -> 394 us.
// R4: fused1 2 nodes/wave + 4-edge ILP + batched softmax.  394 -> 368 us.
// R5: gemm 128x128 reg-blocked (LDS 72KB->16KB).            368 -> 343 us.
// R6: DPP rotate-reduce + exp2 domain; gemm 64x128/4x8.     343 -> 337 us.
// R7: 8-edge unroll flat. R8-R10: degree-sort detour regressed; reverted.
// R11: 3-phase parallel scan (single-block scan was 100us!). 422 -> 329 us.
// R12: xl1 message table bf16 (gather 512->256B/edge).       329 -> 326 us.
// R13: k_fill atomic-free; gemm merged (x@W1l AND x@W1r).    326 -> 282 us.
// R14: GEMM to matrix cores via split-bf16 (hh+hl+lh).       282 -> 277 us.
// R15/16: frag-order pre-pack; 1KB coalesced frag loads.     277 -> 259 us.
// R17: k_fused1 was 54us at 83% VALUBusy (pure VALU-issue bound). Message
//      tables xl1/xr1 moved to F16; logit now packed-f16: v_pk_add_f16 +
//      v_pk_max_f16 + v_dot2_f32_f16 (fdot2) — 20 scalar insts -> 8 packed
//      (+4 cvt for f32 messages). f16 > bf16 mantissa, fdot2 accumulates
//      f32: accuracy comparable/better. xr stream halves. k_fused2
//      re-partitioned 16->4 lanes/node (quad_perm rotate-merge x2): ~2.7x
//      fewer wave-insts.
// ---------------------------------------------------------------------------

#define NGRAPH 64
#define LOG2E 1.4426950408889634f

typedef __attribute__((ext_vector_type(2))) _Float16 hf2;

// v_mov_dpp row_ror:k (16-lane rows). Valid reduce permutation for
// commutative ops; leaves every lane of the row with the full result.
#define DPP_ROR(C, x) \
  __int_as_float(__builtin_amdgcn_update_dpp(0, __float_as_int(x), (0x120 | C), 0xF, 0xF, false))
// quad_perm DPP (ctrl 0x00-0xFF): rotate within 4-lane quads.
#define DPP_QUAD(C, x) \
  __int_as_float(__builtin_amdgcn_update_dpp(0, __float_as_int(x), (C), 0xF, 0xF, false))

__device__ __forceinline__ float rowsum16(float v) {
  v += DPP_ROR(8, v);
  v += DPP_ROR(4, v);
  v += DPP_ROR(2, v);
  v += DPP_ROR(1, v);
  return v;
}

__device__ __forceinline__ unsigned bf16rne(float f) {
  unsigned u = __float_as_uint(f);
  return (u + 0x7FFFu + ((u >> 16) & 1u)) >> 16;
}

__device__ __forceinline__ unsigned short f16u(float f) {
  union { _Float16 h; unsigned short u; } v;
  v.h = (_Float16)f;  // v_cvt_f16_f32, RNE
  return v.u;
}

__device__ __forceinline__ hf2 as_hf2(unsigned u) {
  union { unsigned u; hf2 h; } v;
  v.u = u;
  return v.h;
}

typedef __attribute__((ext_vector_type(8))) short bf16x8;
typedef __attribute__((ext_vector_type(4))) float f32x4;

// ---------------------------------------------------------------------------
// R13: the atomic's return value IS this edge's rank among its dst's edges.
__global__ void k_deg(const int* __restrict__ ei, int E, int Et,
                      int* __restrict__ deg, int* __restrict__ rank) {
  int e = blockIdx.x * blockDim.x + threadIdx.x;
  if (e >= Et) return;
  int d = (e < E) ? ei[E + e] : (e - E);  // dst only
  rank[e] = atomicAdd(&deg[d], 1);        // coalesced store of the rank
}

// ---------------------------------------------------------------------------
// 3-phase parallel exclusive scan of deg[0..n) -> row_ptr[0..n].
__global__ __launch_bounds__(256) void k_scan_part(const int* __restrict__ deg,
                                                   int* __restrict__ bsum, int n) {
  __shared__ int sd[256];
  int t = threadIdx.x;
  int i = blockIdx.x * 1024 + t * 4;
  int s = 0;
  if (i + 4 <= n) {
    int4 d = *(const int4*)&deg[i];
    s = d.x + d.y + d.z + d.w;
  } else {
    for (int j = i; j < min(i + 4, n); ++j) s += deg[j];
  }
  sd[t] = s;
  __syncthreads();
  for (int off = 128; off; off >>= 1) {
    if (t < off) sd[t] += sd[t + off];
    __syncthreads();
  }
  if (t == 0) bsum[blockIdx.x] = sd[0];
}

__global__ __launch_bounds__(64) void k_scan_top(int* __restrict__ bsum, int nb) {
  __shared__ int s[64];
  int t = threadIdx.x;
  s[t] = (t < nb) ? bsum[t] : 0;
  __syncthreads();
  int acc = 0;
  for (int j = 0; j < t; ++j) acc += s[j];
  if (t < nb) bsum[t] = acc;
}

__global__ __launch_bounds__(256) void k_scan_write(const int* __restrict__ deg,
                                                    const int* __restrict__ bsum,
                                                    int* __restrict__ row_ptr, int n) {
  __shared__ int sd[256];
  int t = threadIdx.x;
  int i = blockIdx.x * 1024 + t * 4;
  int4 d = make_int4(0, 0, 0, 0);
  bool full = (i + 4 <= n);
  if (full) d = *(const int4*)&deg[i];
  else {
    if (i + 0 < n) d.x = deg[i + 0];
    if (i + 1 < n) d.y = deg[i + 1];
    if (i + 2 < n) d.z = deg[i + 2];
    if (i + 3 < n) d.w = deg[i + 3];
  }
  int s = d.x + d.y + d.z + d.w;
  sd[t] = s;
  __syncthreads();
  for (int off = 1; off < 256; off <<= 1) {  // Hillis-Steele inclusive
    int v = (t >= off) ? sd[t - off] : 0;
    __syncthreads();
    sd[t] += v;
    __syncthreads();
  }
  int ex = sd[t] - s + bsum[blockIdx.x];
  int4 r;
  r.x = ex;
  r.y = ex + d.x;
  r.z = r.y + d.y;
  r.w = r.z + d.z;
  if (full) {
    *(int4*)&row_ptr[i] = r;
    if (i + 4 == n) row_ptr[n] = r.w + d.w;
  } else if (i < n) {
    int run = ex;
    int vals[4] = {d.x, d.y, d.z, d.w};
    for (int j = 0; j < 4 && i + j < n; ++j) {
      row_ptr[i + j] = run;
      run += vals[j];
    }
    if (i <= n && i + 4 > n) row_ptr[n] = run;
  }
}

// R13: no atomic — slot is row_ptr[d] + precomputed rank.
__global__ void k_fill(const int* __restrict__ ei, int E, int Et,
                       const int* __restrict__ row_ptr,
                       const int* __restrict__ rank,
                       int* __restrict__ csr_src) {
  int e = blockIdx.x * blockDim.x + threadIdx.x;
  if (e >= Et) return;
  int s, d;
  if (e < E) { s = ei[e]; d = ei[E + e]; }
  else       { s = e - E; d = s; }
  csr_src[row_ptr[d] + rank[e]] = s;
}

// ---------------------------------------------------------------------------
// R15 prep: split-bf16 decomposition emitted in MFMA FRAGMENT ORDER.
// Pack layout for a [rows][K=128] matrix: element (rowblk rb, kchunk kc,
// lane l, j) holds M[rb*16 + (l&15)][kc*32 + (l>>4)*8 + j] at linear index
// ((rb*4+kc)*64 + l)*8 + j. A 64-lane fragment load is then 1KB contiguous.
__global__ __launch_bounds__(256) void k_cvt(const float* __restrict__ x,
                                             const float* __restrict__ W1l,
                                             const float* __restrict__ W1r,
                                             unsigned short* __restrict__ xhp,
                                             unsigned short* __restrict__ xlp,
                                             unsigned short* __restrict__ whp,
                                             unsigned short* __restrict__ wlp,
                                             int n, int RB) {
  int t = threadIdx.x;
  int kc = t >> 6;
  int l = t & 63;
  int lr = l & 15;
  int k0 = kc * 32 + (l >> 4) * 8;
  int b = blockIdx.x;
  float f[8];
  if (b < RB) {
    int row = b * 16 + lr;
    if (row < n) {
      float4 a = *(const float4*)&x[(size_t)row * 128 + k0];
      float4 c = *(const float4*)&x[(size_t)row * 128 + k0 + 4];
      f[0] = a.x; f[1] = a.y; f[2] = a.z; f[3] = a.w;
      f[4] = c.x; f[5] = c.y; f[6] = c.z; f[7] = c.w;
    } else {
#pragma unroll
      for (int j = 0; j < 8; ++j) f[j] = 0.f;
    }
  } else {
    int col = (b - RB) * 16 + lr;
#pragma unroll
    for (int j = 0; j < 8; ++j)
      f[j] = (col < 128) ? W1l[(size_t)(k0 + j) * 128 + col]
                         : W1r[(size_t)(k0 + j) * 128 + (col - 128)];
  }
  unsigned hv[8], lv[8];
#pragma unroll
  for (int j = 0; j < 8; ++j) {
    hv[j] = bf16rne(f[j]);
    float r = f[j] - __uint_as_float(hv[j] << 16);
    lv[j] = bf16rne(r);
  }
  uint4 ph, pl;
  ph.x = hv[0] | (hv[1] << 16); ph.y = hv[2] | (hv[3] << 16);
  ph.z = hv[4] | (hv[5] << 16); ph.w = hv[6] | (hv[7] << 16);
  pl.x = lv[0] | (lv[1] << 16); pl.y = lv[2] | (lv[3] << 16);
  pl.z = lv[4] | (lv[5] << 16); pl.w = lv[6] | (lv[7] << 16);
  if (b < RB) {
    size_t slot = (((size_t)b * 4 + kc) * 64 + l) * 8;
    *(uint4*)&xhp[slot] = ph;
    *(uint4*)&xlp[slot] = pl;
  } else {
    size_t slot = (((size_t)(b - RB) * 4 + kc) * 64 + l) * 8;
    *(uint4*)&whp[slot] = ph;
    *(uint4*)&wlp[slot] = pl;
  }
}

// ---------------------------------------------------------------------------
// R15 GEMM on matrix cores, frag-pack operands. Per block: 32 rows x 256
// cols, 4 waves; wave w owns cols [w*64, w*64+64). Waves 0-1 -> xl1 = x@W1l,
// waves 2-3 -> xr1 = x@W1r; R17: BOTH stored as F16 message tables.
// 3 MFMA passes per frag pair: xh*Wh + xh*Wl + xl*Wh (fp32-class accuracy).
__global__ __launch_bounds__(256) void k_gmfma(const unsigned short* __restrict__ xhp,
                                               const unsigned short* __restrict__ xlp,
                                               const unsigned short* __restrict__ whp,
                                               const unsigned short* __restrict__ wlp,
                                               unsigned short* __restrict__ outl,
                                               unsigned short* __restrict__ outr, int n) {
  int w = threadIdx.x >> 6;
  int lane = threadIdx.x & 63;
  int lr = lane & 15;
  int r0 = blockIdx.x * 32;
  int rb0 = blockIdx.x * 2;

  f32x4 acc[2][4] = {};

#pragma unroll
  for (int kc = 0; kc < 4; ++kc) {
    bf16x8 ah[2], al[2], bh[4], bl[4];
#pragma unroll
    for (int m = 0; m < 2; ++m) {
      size_t slot = (((size_t)(rb0 + m) * 4 + kc) * 64 + lane) * 8;
      ah[m] = *(const bf16x8*)&xhp[slot];
      al[m] = *(const bf16x8*)&xlp[slot];
    }
#pragma unroll
    for (int f = 0; f < 4; ++f) {
      size_t slot = (((size_t)(w * 4 + f) * 4 + kc) * 64 + lane) * 8;
      bh[f] = *(const bf16x8*)&whp[slot];
      bl[f] = *(const bf16x8*)&wlp[slot];
    }
#pragma unroll
    for (int m = 0; m < 2; ++m)
#pragma unroll
      for (int f = 0; f < 4; ++f) {
        acc[m][f] = __builtin_amdgcn_mfma_f32_16x16x32_bf16(ah[m], bh[f], acc[m][f], 0, 0, 0);
        acc[m][f] = __builtin_amdgcn_mfma_f32_16x16x32_bf16(ah[m], bl[f], acc[m][f], 0, 0, 0);
        acc[m][f] = __builtin_amdgcn_mfma_f32_16x16x32_bf16(al[m], bh[f], acc[m][f], 0, 0, 0);
      }
  }

  int rbase = (lane >> 4) * 4;
  unsigned short* dst = (w < 2) ? outl : outr;
  int cb = (w & 1) * 64;
#pragma unroll
  for (int m = 0; m < 2; ++m)
#pragma unroll
    for (int f = 0; f < 4; ++f) {
      int col = cb + f * 16 + lr;
#pragma unroll
      for (int i = 0; i < 4; ++i) {
        int row = r0 + m * 16 + rbase + i;
        if (row < n)
          dst[(size_t)row * 128 + col] = f16u(acc[m][f][i]);
      }
    }
}

// ---------------------------------------------------------------------------
// fused layer-1 edge phase + layer-2 input projection.
// TWO nodes per wave: lanes 0-31 = node 2w, 32-63 = node 2w+1. Lane holds 4
// channels; 16-lane head groups = DPP rows. 4 edges/iter.
// R17: xl AND xr are F16 tables; logit via packed-f16 (v_pk_add/max_f16 +
// v_dot2_f32_f16); messages recovered to f32 via v_cvt; softmax/acc in f32.
__global__ __launch_bounds__(256) void k_fused1(const unsigned short* __restrict__ xl,
                                                const unsigned short* __restrict__ xr,
                                                const int* __restrict__ row_ptr,
                                                const int* __restrict__ csr_src,
                                                const float* __restrict__ att1,
                                                const float* __restrict__ b1,
                                                const float* __restrict__ W2l,
                                                const float* __restrict__ W2r,
                                                float* __restrict__ xl2,
                                                float* __restrict__ xr2, int n) {
  int wid  = (blockIdx.x * 256 + threadIdx.x) >> 6;
  int lane = threadIdx.x & 63;
  int sub  = lane & 31;
  int node = min(wid * 2 + (lane >> 5), n - 1);  // dup of last node is benign
  int ch = sub * 4;
  const char* xlb = (const char*)xl;
  unsigned chb = (unsigned)sub * 8u;  // byte offset within 256B f16 row

  uint2 xrq = *(const uint2*)&xr[(size_t)node * 128 + ch];
  hf2 xr01 = as_hf2(xrq.x), xr23 = as_hf2(xrq.y);
  float4 atv = *(const float4*)&att1[ch];
  hf2 at01, at23;
  at01.x = (_Float16)(atv.x * LOG2E); at01.y = (_Float16)(atv.y * LOG2E);
  at23.x = (_Float16)(atv.z * LOG2E); at23.y = (_Float16)(atv.w * LOG2E);
  hf2 k02; k02.x = (_Float16)0.2f; k02.y = (_Float16)0.2f;

  int s0 = row_ptr[node];
  int deg = row_ptr[node + 1] - s0;  // >=1 (self-loop)
  int odeg = __shfl_xor(deg, 32);
  int mindeg = min(deg, odeg);  // wave-uniform
  int maxdeg = max(deg, odeg);  // wave-uniform
  const int* sp = csr_src + s0;

  float m = -1e30f, l = 0.f;
  float4 acc = make_float4(0.f, 0.f, 0.f, 0.f);

// per-edge: packed-f16 logit + f32 message recovery
#define EDGE(p, x0, x1, x2, x3, q)                                      \
    { hf2 v01 = as_hf2(q.x), v23 = as_hf2(q.y);                         \
      hf2 t01 = v01 + xr01, t23 = v23 + xr23;                           \
      hf2 l01 = __builtin_elementwise_max(t01, t01 * k02);              \
      hf2 l23 = __builtin_elementwise_max(t23, t23 * k02);              \
      p = __builtin_amdgcn_fdot2(l23, at23,                             \
            __builtin_amdgcn_fdot2(l01, at01, 0.f, false), false);      \
      x0 = (float)l01.x; /* placeholder overwritten below */            \
      x0 = (float)v01.x; x1 = (float)v01.y;                             \
      x2 = (float)v23.x; x3 = (float)v23.y; }

#define BODY(CLAMPED)                                                   \
  {                                                                     \
    int sA, sB, sC, sD;                                                 \
    if (CLAMPED) {                                                      \
      int dm1 = deg - 1;                                                \
      sA = sp[min(e + 0, dm1)];                                         \
      sB = sp[min(e + 1, dm1)];                                         \
      sC = sp[min(e + 2, dm1)];                                         \
      sD = sp[min(e + 3, dm1)];                                         \
    } else {                                                            \
      sA = sp[e + 0]; sB = sp[e + 1]; sC = sp[e + 2]; sD = sp[e + 3];   \
    }                                                                   \
    uint2 qa = *(const uint2*)(xlb + (((unsigned)sA << 8) + chb));      \
    uint2 qb = *(const uint2*)(xlb + (((unsigned)sB << 8) + chb));      \
    uint2 qc = *(const uint2*)(xlb + (((unsigned)sC << 8) + chb));      \
    uint2 qd = *(const uint2*)(xlb + (((unsigned)sD << 8) + chb));      \
    float pa, pb, pc, pd;                                               \
    float xa0, xa1, xa2, xa3, xb0, xb1, xb2, xb3;                       \
    float xc0, xc1, xc2, xc3, xd0, xd1, xd2, xd3;                       \
    EDGE(pa, xa0, xa1, xa2, xa3, qa)                                    \
    EDGE(pb, xb0, xb1, xb2, xb3, qb)                                    \
    EDGE(pc, xc0, xc1, xc2, xc3, qc)                                    \
    EDGE(pd, xd0, xd1, xd2, xd3, qd)                                    \
    pa = rowsum16(pa);                                                  \
    pb = rowsum16(pb);                                                  \
    pc = rowsum16(pc);                                                  \
    pd = rowsum16(pd);                                                  \
    if (CLAMPED) {                                                      \
      pa = (e + 0 < deg) ? pa : -1e30f;                                 \
      pb = (e + 1 < deg) ? pb : -1e30f;                                 \
      pc = (e + 2 < deg) ? pc : -1e30f;                                 \
      pd = (e + 3 < deg) ? pd : -1e30f;                                 \
    }                                                                   \
    float mn = fmaxf(m, fmaxf(fmaxf(pa, pb), fmaxf(pc, pd)));           \
    float sc = exp2f(m - mn);                                           \
    float wa = exp2f(pa - mn);                                          \
    float wb = exp2f(pb - mn);                                          \
    float wc = exp2f(pc - mn);                                          \
    float wd = exp2f(pd - mn);                                          \
    acc.x = fmaf(wd, xd0, fmaf(wc, xc0, fmaf(wb, xb0, fmaf(wa, xa0, acc.x * sc)))); \
    acc.y = fmaf(wd, xd1, fmaf(wc, xc1, fmaf(wb, xb1, fmaf(wa, xa1, acc.y * sc)))); \
    acc.z = fmaf(wd, xd2, fmaf(wc, xc2, fmaf(wb, xb2, fmaf(wa, xa2, acc.z * sc)))); \
    acc.w = fmaf(wd, xd3, fmaf(wc, xc3, fmaf(wb, xb3, fmaf(wa, xa3, acc.w * sc)))); \
    l = fmaf(l, sc, wa + wb + wc + wd);                                 \
    m = mn;                                                             \
  }

  int e = 0;
  for (; e + 4 <= mindeg; e += 4) BODY(false)
  for (; e < maxdeg; e += 4) BODY(true)
#undef BODY
#undef EDGE

  float inv = 1.f / (l + 1e-16f);
  float4 b1v = *(const float4*)&b1[ch];
  float4 h;
  h.x = acc.x * inv + b1v.x; h.x = h.x > 0.f ? h.x : expm1f(h.x);
  h.y = acc.y * inv + b1v.y; h.y = h.y > 0.f ? h.y : expm1f(h.y);
  h.z = acc.z * inv + b1v.z; h.z = h.z > 0.f ? h.z : expm1f(h.z);
  h.w = acc.w * inv + b1v.w; h.w = h.w > 0.f ? h.w : expm1f(h.w);

  float4 u0 = *(const float4*)&W2l[ch * 3 + 0];
  float4 u1 = *(const float4*)&W2l[ch * 3 + 4];
  float4 u2 = *(const float4*)&W2l[ch * 3 + 8];
  float al0 = fmaf(h.w, u2.y, fmaf(h.z, u1.z, fmaf(h.y, u0.w, h.x * u0.x)));
  float al1 = fmaf(h.w, u2.z, fmaf(h.z, u1.w, fmaf(h.y, u1.x, h.x * u0.y)));
  float al2 = fmaf(h.w, u2.w, fmaf(h.z, u2.x, fmaf(h.y, u1.y, h.x * u0.z)));
  float4 v0 = *(const float4*)&W2r[ch * 3 + 0];
  float4 v1 = *(const float4*)&W2r[ch * 3 + 4];
  float4 v2 = *(const float4*)&W2r[ch * 3 + 8];
  float ar0 = fmaf(h.w, v2.y, fmaf(h.z, v1.z, fmaf(h.y, v0.w, h.x * v0.x)));
  float ar1 = fmaf(h.w, v2.z, fmaf(h.z, v1.w, fmaf(h.y, v1.x, h.x * v0.y)));
  float ar2 = fmaf(h.w, v2.w, fmaf(h.z, v2.x, fmaf(h.y, v1.y, h.x * v0.z)));
#pragma unroll
  for (int off = 1; off < 32; off <<= 1) {
    al0 += __shfl_xor(al0, off); al1 += __shfl_xor(al1, off);
    al2 += __shfl_xor(al2, off); ar0 += __shfl_xor(ar0, off);
    ar1 += __shfl_xor(ar1, off); ar2 += __shfl_xor(ar2, off);
  }
  if (sub == 0 && wid * 2 + (lane >> 5) < n) {
    *(float4*)&xl2[node * 4] = make_float4(al0, al1, al2, 0.f);
    *(float4*)&xr2[node * 4] = make_float4(ar0, ar1, ar2, 0.f);
  }
}

// ---------------------------------------------------------------------------
// fused layer-2 edge phase + mean-pool. R17: FOUR lanes per node (16 nodes
// per wave) — deg~17 means each lane now runs ~4 serial online-softmax steps
// instead of ~1, and the cross-lane merge shrinks from 4 DPP steps to 2
// quad_perm rotations. Pool pre-reduced in LDS.
__global__ __launch_bounds__(256) void k_fused2(const float* __restrict__ xl2,
                                                const float* __restrict__ xr2,
                                                const int* __restrict__ row_ptr,
                                                const int* __restrict__ csr_src,
                                                const float* __restrict__ att2,
                                                const float* __restrict__ b2,
                                                const int* __restrict__ batch,
                                                float* __restrict__ gsum,
                                                float* __restrict__ gcnt, int n) {
  __shared__ float ls[NGRAPH * 3];
  __shared__ float lc[NGRAPH];
  int t = threadIdx.x;
  for (int i = t; i < NGRAPH * 3; i += 256) ls[i] = 0.f;
  for (int i = t; i < NGRAPH; i += 256) lc[i] = 0.f;
  __syncthreads();

  int node = (blockIdx.x * 256 + t) >> 2;  // 64 nodes per block
  int lane = t & 3;
  if (node < n) {
    float4 xrv = *(const float4*)&xr2[node * 4];
    float c0 = att2[0] * LOG2E, c1 = att2[1] * LOG2E, c2 = att2[2] * LOG2E;
    int s0 = row_ptr[node], s1 = row_ptr[node + 1];
    float m = -1e30f, l = 0.f, a0 = 0.f, a1 = 0.f, a2 = 0.f;
    for (int slot = s0 + lane; slot < s1; slot += 4) {
      int s = csr_src[slot];
      float4 xlv = *(const float4*)&xl2[s * 4];
      float t0 = xlv.x + xrv.x; t0 = fmaxf(t0, 0.2f * t0);
      float t1 = xlv.y + xrv.y; t1 = fmaxf(t1, 0.2f * t1);
      float t2 = xlv.z + xrv.z; t2 = fmaxf(t2, 0.2f * t2);
      float p = fmaf(t2, c2, fmaf(t1, c1, t0 * c0));
      float mn = fmaxf(m, p);
      float sc = exp2f(m - mn);
      float w  = exp2f(p - mn);
      a0 = a0 * sc + w * xlv.x;
      a1 = a1 * sc + w * xlv.y;
      a2 = a2 * sc + w * xlv.z;
      l = l * sc + w;
      m = mn;
    }
    // rotate-merge within each 4-lane quad: rot-by-1 (0x39) then rot-by-2
    // (0x4E); every lane ends with the full node state.
#define MERGEQ(C)                                                       \
    {                                                                   \
      float m2 = DPP_QUAD(C, m);                                        \
      float l2 = DPP_QUAD(C, l);                                        \
      float b0 = DPP_QUAD(C, a0);                                       \
      float b1v = DPP_QUAD(C, a1);                                      \
      float b2v = DPP_QUAD(C, a2);                                      \
      float mn = fmaxf(m, m2);                                          \
      float sA = exp2f(m - mn);                                         \
      float sB = exp2f(m2 - mn);                                        \
      a0 = a0 * sA + b0 * sB;                                           \
      a1 = a1 * sA + b1v * sB;                                          \
      a2 = a2 * sA + b2v * sB;                                          \
      l = l * sA + l2 * sB;                                             \
      m = mn;                                                           \
    }
    MERGEQ(0x39) MERGEQ(0x4E)
#undef MERGEQ
    if (lane == 0) {
      float inv = 1.f / (l + 1e-16f);
      float o0 = a0 * inv + b2[0];
      float o1 = a1 * inv + b2[1];
      float o2 = a2 * inv + b2[2];
      int b = batch[node];
      atomicAdd(&ls[b * 3 + 0], o0);
      atomicAdd(&ls[b * 3 + 1], o1);
      atomicAdd(&ls[b * 3 + 2], o2);
      atomicAdd(&lc[b], 1.f);
    }
  }
  __syncthreads();
  for (int i = t; i < NGRAPH * 3; i += 256)
    if (ls[i] != 0.f) atomicAdd(&gsum[i], ls[i]);
  for (int i = t; i < NGRAPH; i += 256)
    if (lc[i] != 0.f) atomicAdd(&gcnt[i], lc[i]);
}

// 1 block, 64 threads: per-graph mean + 2-layer MLP
__global__ __launch_bounds__(64) void k_mlp(const float* __restrict__ gsum,
                                            const float* __restrict__ gcnt,
                                            const float* __restrict__ Wr1,
                                            const float* __restrict__ br1,
                                            const float* __restrict__ Wr2,
                                            const float* __restrict__ br2,
                                            float* __restrict__ out) {
  int t = threadIdx.x;
  if (t >= NGRAPH) return;
  float cnt = fmaxf(gcnt[t], 1.f);
  float g0 = gsum[t * 3 + 0] / cnt;
  float g1 = gsum[t * 3 + 1] / cnt;
  float g2 = gsum[t * 3 + 2] / cnt;
  float o0 = br2[0], o1 = br2[1], o2 = br2[2];
  for (int j = 0; j < 64; ++j) {
    float hj = g0 * Wr1[j] + g1 * Wr1[64 + j] + g2 * Wr1[128 + j] + br1[j];
    hj = fmaxf(hj, 0.f);
    o0 = fmaf(hj, Wr2[j * 3 + 0], o0);
    o1 = fmaf(hj, Wr2[j * 3 + 1], o1);
    o2 = fmaf(hj, Wr2[j * 3 + 2], o2);
  }
  out[t * 3 + 0] = o0;
  out[t * 3 + 1] = o1;
  out[t * 3 + 2] = o2;
}

// ---------------------------------------------------------------------------
extern "C" void kernel_launch(void* const* d_in, const int* in_sizes, int n_in,
                              void* d_out, int out_size, void* d_ws, size_t ws_size,
                              hipStream_t stream) {
  const float* x    = (const float*)d_in[0];
  const int*   ei   = (const int*)d_in[1];
  const int*   batch= (const int*)d_in[2];
  const float* W1l  = (const float*)d_in[3];
  const float* W1r  = (const float*)d_in[4];
  const float* att1 = (const float*)d_in[5];
  const float* b1   = (const float*)d_in[6];
  const float* W2l  = (const float*)d_in[7];
  const float* W2r  = (const float*)d_in[8];
  const float* att2 = (const float*)d_in[9];
  const float* b2   = (const float*)d_in[10];
  const float* Wr1  = (const float*)d_in[11];
  const float* br1  = (const float*)d_in[12];
  const float* Wr2  = (const float*)d_in[13];
  const float* br2  = (const float*)d_in[14];
  float* out = (float*)d_out;

  const int N  = in_sizes[0] / 128;
  const int E  = in_sizes[1] / 2;
  const int Et = E + N;
  const int NB = (N + 1023) / 1024;  // scan blocks (<=64)
  const int NB32 = (N + 31) / 32;    // gmfma blocks
  const int RB = NB32 * 2;           // padded 16-row blocks in the A-pack

  char* p = (char*)d_ws;
  auto alloc = [&](size_t bytes) -> char* {
    char* r = p;
    p += (bytes + 255) & ~(size_t)255;
    return r;
  };
  unsigned short* xl1 = (unsigned short*)alloc((size_t)N * 128 * 2);  // f16
  unsigned short* xr1 = (unsigned short*)alloc((size_t)N * 128 * 2);  // f16
  int*      row_ptr= (int*)alloc((size_t)(N + 1) * 4);
  int*      csr_src= (int*)alloc((size_t)Et * 4);
  int*      rank   = (int*)alloc((size_t)Et * 4);
  int*      bsum   = (int*)alloc(64 * 4);
  // zero-init group (one memset): deg | gsum | gcnt
  char*     z0     = p;
  int*      deg    = (int*)alloc((size_t)N * 4);
  float*    gsum   = (float*)alloc(NGRAPH * 3 * 4);
  float*    gcnt   = (float*)alloc(NGRAPH * 4);
  size_t    zbytes = (size_t)(p - z0);
  float*    xl2    = (float*)alloc((size_t)N * 4 * 4);
  float*    xr2    = (float*)alloc((size_t)N * 4 * 4);
  // R15: frag-packed split-bf16 operands for the matrix-core GEMM
  unsigned short* xhp = (unsigned short*)alloc((size_t)RB * 2048 * 2);
  unsigned short* xlp = (unsigned short*)alloc((size_t)RB * 2048 * 2);
  unsigned short* whp = (unsigned short*)alloc((size_t)16 * 2048 * 2);
  unsigned short* wlp = (unsigned short*)alloc((size_t)16 * 2048 * 2);

  hipMemsetAsync(z0, 0, zbytes, stream);
  hipLaunchKernelGGL(k_deg, dim3((Et + 255) / 256), dim3(256), 0, stream,
                     ei, E, Et, deg, rank);
  hipLaunchKernelGGL(k_scan_part, dim3(NB), dim3(256), 0, stream, deg, bsum, N);
  hipLaunchKernelGGL(k_scan_top, dim3(1), dim3(64), 0, stream, bsum, NB);
  hipLaunchKernelGGL(k_scan_write, dim3(NB), dim3(256), 0, stream,
                     deg, bsum, row_ptr, N);
  hipLaunchKernelGGL(k_fill, dim3((Et + 255) / 256), dim3(256), 0, stream,
                     ei, E, Et, row_ptr, rank, csr_src);
  hipLaunchKernelGGL(k_cvt, dim3(RB + 16), dim3(256), 0, stream,
                     x, W1l, W1r, xhp, xlp, whp, wlp, N, RB);
  hipLaunchKernelGGL(k_gmfma, dim3(NB32), dim3(256), 0, stream,
                     xhp, xlp, whp, wlp, xl1, xr1, N);
  int waves1 = (N + 1) / 2;
  hipLaunchKernelGGL(k_fused1, dim3((waves1 * 64 + 255) / 256), dim3(256), 0, stream,
                     xl1, xr1, row_ptr, csr_src, att1, b1, W2l, W2r, xl2, xr2, N);
  hipLaunchKernelGGL(k_fused2, dim3((N * 4 + 255) / 256), dim3(256), 0, stream,
                     xl2, xr2, row_ptr, csr_src, att2, b2, batch, gsum, gcnt, N);
  hipLaunchKernelGGL(k_mlp, dim3(1), dim3(64), 0, stream,
                     gsum, gcnt, Wr1, br1, Wr2, br2, out);
}